// Round 12
// baseline (579.132 us; speedup 1.0000x reference)
//
#include <hip/hip_runtime.h>
#include <hip/hip_cooperative_groups.h>
#include <stdint.h>

namespace cg = cooperative_groups;

#define N_UNITS   400
#define N_NEIGHB  64
#define C         3
#define S         2
#define T         10      // C + C*S + E, E=1
#define BS        256
#define GB        512     // cooperative grid blocks (2/CU x 256 CUs)
#define SLICE_A   256     // phase-A slices (GB/2)
#define HALF_NB   32
#define HH        (HALF_NB * N_UNITS)   // 12800 packed words
#define EH        (N_UNITS * 32)        // 12800 packed words (64 nb in 16-bit pairs)
#define SMEMW     14064                 // 56.3 KB shared (union of all phases)

// fallback (round-11 verified) params
#define NSLICE_A  128
#define MB        512

// ---------- JAX Threefry-2x32, key = (0, 1) (jax.random.key(1)) ----------
__device__ __forceinline__ uint32_t rotl32(uint32_t x, int d) {
    return (x << d) | (x >> (32 - d));
}

__device__ __forceinline__ void threefry_key01(uint32_t x0, uint32_t x1,
                                               uint32_t& o0, uint32_t& o1) {
    const uint32_t ks0 = 0u;
    const uint32_t ks1 = 1u;
    const uint32_t ks2 = 0x1BD11BDBu;  // 0x1BD11BDA ^ 0 ^ 1
    x0 += ks0; x1 += ks1;
#define TF_RND(r) { x0 += x1; x1 = rotl32(x1, r); x1 ^= x0; }
    TF_RND(13) TF_RND(15) TF_RND(26) TF_RND(6)
    x0 += ks1; x1 += ks2 + 1u;
    TF_RND(17) TF_RND(29) TF_RND(16) TF_RND(24)
    x0 += ks2; x1 += ks0 + 2u;
    TF_RND(13) TF_RND(15) TF_RND(26) TF_RND(6)
    x0 += ks0; x1 += ks1 + 3u;
    TF_RND(17) TF_RND(29) TF_RND(16) TF_RND(24)
    x0 += ks1; x1 += ks2 + 4u;
    TF_RND(13) TF_RND(15) TF_RND(26) TF_RND(6)
    x0 += ks2; x1 += ks0 + 5u;
#undef TF_RND
    o0 = x0; o1 = x1;
}

// jax_threefry_partitionable=True (default since jax 0.4.36):
// bits[i] = x0 ^ x1 of threefry2x32(key, (i >> 32, i & 0xffffffff)).
__device__ __forceinline__ int explore_index(int i, int ne) {
    uint32_t o0, o1;
    threefry_key01(0u, (uint32_t)i, o0, o1);
    uint32_t bits = o0 ^ o1;
    float u = __uint_as_float((bits >> 9) | 0x3F800000u) - 1.0f;
    int t = (int)floorf(u * (float)ne);
    return min(t, ne - 1);
}

// ===================== fused cooperative kernel ===========================
__global__ __launch_bounds__(BS, 2)
void k_fused(const float* __restrict__ logliks,
             const int* __restrict__ top,
             const int* __restrict__ usn,
             const int* __restrict__ nbid,
             int* __restrict__ wtbl, int* __restrict__ wne,
             uint32_t* __restrict__ PA, uint32_t* __restrict__ PD,
             uint32_t* __restrict__ Hsum,
             float* out_counts,
             float* __restrict__ out_cand,
             float* __restrict__ out_scores,
             int n, int chunkA, int chunkM) {
    __shared__ uint32_t smem[SMEMW];
    cg::grid_group grid = cg::this_grid();
    int tid = threadIdx.x;
    int b = blockIdx.x;

    // ---- Phase A: packed top-column partial histograms -------------------
    {
        uint32_t* hist = smem;
        for (int k = tid; k < HH; k += BS) hist[k] = 0u;
        __syncthreads();
        int h = b & 1, s = b >> 1;
        int lo = s * chunkA, hi = min(n, lo + chunkA);
        const int4* top4 = (const int4*)top;
#define PROC(nb, t0, t1, t2) if (((nb) >> 5) == h) { \
    int r = ((nb) & 31) * N_UNITS; \
    atomicAdd(&hist[r + (t0)], 1u); \
    atomicAdd(&hist[r + (t1)], 0x10000u); \
    atomicAdd(&hist[r + (t2)], 0x10000u); }
        for (int i0 = lo + tid * 4; i0 < hi; i0 += BS * 4) {
            if (i0 + 4 <= hi) {
                int4 nb4 = *(const int4*)(nbid + i0);
                int j = (i0 * 3) >> 2;
                int4 ta = top4[j], tb = top4[j + 1], tc = top4[j + 2];
                PROC(nb4.x, ta.x, ta.y, ta.z)
                PROC(nb4.y, ta.w, tb.x, tb.y)
                PROC(nb4.z, tb.z, tb.w, tc.x)
                PROC(nb4.w, tc.y, tc.z, tc.w)
            } else {
                for (int i = i0; i < hi; ++i)
                    PROC(nbid[i], top[3 * i], top[3 * i + 1], top[3 * i + 2])
            }
        }
#undef PROC
        __syncthreads();
        uint32_t* Pb = PA + (size_t)b * HH;
        for (int k = tid; k < HH; k += BS) Pb[k] = hist[k];
    }
    __threadfence();
    grid.sync();

    // ---- Phase B1: column-reduce PA -> Hsum (packed [64][400]) -----------
    {
        int c = b * BS + tid;
        if (c < N_NEIGHB * N_UNITS) {
            int nb = c / N_UNITS, u = c - nb * N_UNITS;
            int h = nb >> 5, base = (nb & 31) * N_UNITS + u;
            uint32_t sum = 0;
#pragma unroll 8
            for (int s = 0; s < SLICE_A; ++s)
                sum += PA[(size_t)(s * 2 + h) * HH + base];
            Hsum[c] = sum;
        }
    }
    __threadfence();
    grid.sync();

    // ---- Phase B2: tables + base counts (blocks 0..63) -------------------
    if (b < N_NEIGHB) {
        uint32_t* bufA = smem;                    // 400 (scan ping)
        uint32_t* bufB = smem + 512;              // 400 (scan pong)
        int* s_c  = (int*)(smem + 1024);          // 400
        int* s_h3 = (int*)(smem + 1536);          // 400
        int* s_p  = (int*)(smem + 2048);          // 400
        for (int u = tid; u < N_UNITS; u += BS) {
            uint32_t w = Hsum[b * N_UNITS + u];
            int h0 = (int)(w & 0xFFFFu), h12 = (int)(w >> 16);
            int h3 = h0 + h12;
            s_h3[u] = h3;
            s_c[u]  = h3;                          // top0 + top1/top2
            s_p[u]  = (h0 > 0) ? 1 : 0;
            bufA[u] = (uint32_t)s_p[u];
        }
        __syncthreads();
        uint32_t* src = bufA; uint32_t* dst = bufB;
        for (int off = 1; off < 512; off <<= 1) {  // 9-step inclusive scan
            for (int u = tid; u < N_UNITS; u += BS)
                dst[u] = src[u] + ((u >= off) ? src[u - off] : 0u);
            __syncthreads();
            uint32_t* t = src; src = dst; dst = t;
        }
        for (int u = tid; u < N_UNITS; u += BS)
            if (s_p[u]) wtbl[b * N_UNITS + (int)src[u] - 1] = u;
        if (tid == 0) wne[b] = (int)src[N_UNITS - 1];
        __syncthreads();
        for (int u = tid; u < N_UNITS; u += BS) {
            int h3 = s_h3[u];
            if (h3 > 0) {
                int2 nbr = ((const int2*)usn)[u];
                atomicAdd(&s_c[nbr.x], h3);
                atomicAdd(&s_c[nbr.y], h3);
            }
        }
        __syncthreads();
        for (int u = tid; u < N_UNITS; u += BS)
            out_counts[u * N_NEIGHB + b] = (float)s_c[u];
    }
    __threadfence();
    grid.sync();

    // ---- Phase C: candidates + scores + explore LDS histogram ------------
    {
        uint32_t* hist  = smem;                        // 12800
        int*      s_usn = (int*)(smem + EH);           // 800
        float*    s_ll  = (float*)(smem + EH + 800);   // 400
        int*      s_ne  = (int*)(smem + EH + 1200);    // 64
        for (int k = tid; k < EH; k += BS) hist[k] = 0u;
        for (int k = tid; k < N_UNITS * S; k += BS) s_usn[k] = usn[k];
        for (int k = tid; k < N_UNITS; k += BS)     s_ll[k]  = logliks[k];
        for (int k = tid; k < N_NEIGHB; k += BS)    s_ne[k]  = wne[k];
        __syncthreads();
        int lo = b * chunkM, hi = min(n, lo + chunkM);
        for (int i = lo + tid; i < hi; i += BS) {
            int nb = nbid[i];
            int cand[T];
            cand[0] = top[i * 3 + 0];
            cand[1] = top[i * 3 + 1];
            cand[2] = top[i * 3 + 2];
#pragma unroll
            for (int c = 0; c < C; ++c) {
                cand[C + 2 * c]     = s_usn[cand[c] * 2 + 0];
                cand[C + 2 * c + 1] = s_usn[cand[c] * 2 + 1];
            }
            int ne = s_ne[nb];
            if (ne > 0) {
                int t = explore_index(i, ne);
                int ex = wtbl[nb * N_UNITS + t];
                cand[T - 1] = ex;
                atomicAdd(&hist[ex * 32 + (nb >> 1)], (nb & 1) ? 0x10000u : 1u);
            } else {
                cand[T - 1] = -1;
            }
            float vc[T], vs[T];
#pragma unroll
            for (int jj = 0; jj < T; ++jj) {
                bool dup = false;
#pragma unroll
                for (int k = 0; k < jj; ++k) dup |= (cand[k] == cand[jj]);
                int v = dup ? -1 : cand[jj];   // reference erases dups to -1
                vc[jj] = (float)v;
                vs[jj] = (v >= 0) ? s_ll[v] : 0.0f;
            }
            float2* oc2 = (float2*)(out_cand   + (size_t)i * T);
            float2* os2 = (float2*)(out_scores + (size_t)i * T);
#pragma unroll
            for (int jj = 0; jj < T / 2; ++jj) {
                oc2[jj] = make_float2(vc[2 * jj], vc[2 * jj + 1]);
                os2[jj] = make_float2(vs[2 * jj], vs[2 * jj + 1]);
            }
        }
        __syncthreads();
        uint32_t* Pb = PD + (size_t)b * EH;
        for (int k = tid; k < EH; k += BS) Pb[k] = hist[k];
    }
    __threadfence();
    grid.sync();

    // ---- Phase D: reduce explore partials into out_counts (blocks 0..199)-
    if (b < EH / 64) {
        uint32_t* red = smem;
        int wl = tid & 63, g = tid >> 6;
        int w = b * 64 + wl;
        uint32_t sum = 0;
#pragma unroll 8
        for (int s = g * (GB / 4); s < (g + 1) * (GB / 4); ++s)
            sum += PD[(size_t)s * EH + w];
        red[tid] = sum;
        __syncthreads();
        if (g == 0) {
            uint32_t tot = red[wl] + red[wl + 64] + red[wl + 128] + red[wl + 192];
            int u = w >> 5, nb2 = (w & 31) * 2;
            float2* p = (float2*)(out_counts + u * N_NEIGHB + nb2);
            float2 v = *p;
            v.x += (float)(tot & 0xFFFFu);
            v.y += (float)(tot >> 16);
            *p = v;
        }
    }
}

// ===================== fallback: round-11 verified 4-kernel path ==========
__global__ void k_histA(const int* __restrict__ top,
                        const int* __restrict__ nbid,
                        uint32_t* __restrict__ PA, int n, int chunk) {
    __shared__ uint32_t hist[HH];
    for (int k = threadIdx.x; k < HH; k += blockDim.x) hist[k] = 0u;
    __syncthreads();
    int h = blockIdx.x & 1, s = blockIdx.x >> 1;
    int lo = s * chunk, hi = min(n, lo + chunk);
    const int4* top4 = (const int4*)top;
#define PROC(nb, t0, t1, t2) if (((nb) >> 5) == h) { \
    int r = ((nb) & 31) * N_UNITS; \
    atomicAdd(&hist[r + (t0)], 1u); \
    atomicAdd(&hist[r + (t1)], 0x10000u); \
    atomicAdd(&hist[r + (t2)], 0x10000u); }
    for (int i0 = lo + threadIdx.x * 4; i0 < hi; i0 += blockDim.x * 4) {
        if (i0 + 4 <= hi) {
            int4 nb4 = *(const int4*)(nbid + i0);
            int j = (i0 * 3) >> 2;
            int4 ta = top4[j], tb = top4[j + 1], tc = top4[j + 2];
            PROC(nb4.x, ta.x, ta.y, ta.z)
            PROC(nb4.y, ta.w, tb.x, tb.y)
            PROC(nb4.z, tb.z, tb.w, tc.x)
            PROC(nb4.w, tc.y, tc.z, tc.w)
        } else {
            for (int i = i0; i < hi; ++i)
                PROC(nbid[i], top[3 * i], top[3 * i + 1], top[3 * i + 2])
        }
    }
#undef PROC
    __syncthreads();
    uint32_t* Pb = PA + (size_t)blockIdx.x * HH;
    for (int k = threadIdx.x; k < HH; k += blockDim.x) Pb[k] = hist[k];
}

__global__ void k_tables_base(const uint32_t* __restrict__ PA,
                              const int* __restrict__ usn,
                              int* __restrict__ wtbl,
                              int* __restrict__ wne,
                              float* __restrict__ out_counts) {
    __shared__ int scan[512];
    __shared__ int s_c[N_UNITS];
    __shared__ int s_h3[N_UNITS];
    int b = blockIdx.x, u = threadIdx.x;
    int h = b >> 5;
    int base = (b & 31) * N_UNITS;
    int h0 = 0, h12 = 0;
    if (u < N_UNITS) {
#pragma unroll 8
        for (int s = 0; s < NSLICE_A; ++s) {
            uint32_t w = PA[(size_t)(s * 2 + h) * HH + base + u];
            h0  += (int)(w & 0xFFFFu);
            h12 += (int)(w >> 16);
        }
        int h3 = h0 + h12;
        s_h3[u] = h3;
        s_c[u] = h3;
    }
    int p = (u < N_UNITS && h0 > 0) ? 1 : 0;
    scan[u] = p;
    __syncthreads();
    for (int off = 1; off < 512; off <<= 1) {
        int add = (u >= off) ? scan[u - off] : 0;
        __syncthreads();
        scan[u] += add;
        __syncthreads();
    }
    if (p) wtbl[b * N_UNITS + scan[u] - 1] = u;
    if (u == 511) wne[b] = scan[511];
    if (u < N_UNITS) {
        int h3 = s_h3[u];
        if (h3 > 0) {
            int2 nbr = ((const int2*)usn)[u];
            atomicAdd(&s_c[nbr.x], h3);
            atomicAdd(&s_c[nbr.y], h3);
        }
    }
    __syncthreads();
    if (u < N_UNITS)
        out_counts[u * N_NEIGHB + b] = (float)s_c[u];
}

__global__ void k_main(const float* __restrict__ logliks,
                       const int* __restrict__ top,
                       const int* __restrict__ usn,
                       const int* __restrict__ nbid,
                       const int* __restrict__ wtbl,
                       const int* __restrict__ wne,
                       uint32_t* __restrict__ PD,
                       float* __restrict__ out_cand,
                       float* __restrict__ out_scores,
                       int n, int chunk) {
    __shared__ uint32_t hist[EH];
    __shared__ int   s_usn[N_UNITS * S];
    __shared__ float s_ll[N_UNITS];
    __shared__ int   s_ne[N_NEIGHB];
    int tid = threadIdx.x;
    for (int k = tid; k < EH; k += BS) hist[k] = 0u;
    for (int k = tid; k < N_UNITS * S; k += BS) s_usn[k] = usn[k];
    for (int k = tid; k < N_UNITS; k += BS)     s_ll[k]  = logliks[k];
    for (int k = tid; k < N_NEIGHB; k += BS)    s_ne[k]  = wne[k];
    __syncthreads();
    int lo = blockIdx.x * chunk, hi = min(n, lo + chunk);
    for (int i = lo + tid; i < hi; i += BS) {
        int nb = nbid[i];
        int cand[T];
        cand[0] = top[i * 3 + 0];
        cand[1] = top[i * 3 + 1];
        cand[2] = top[i * 3 + 2];
#pragma unroll
        for (int c = 0; c < C; ++c) {
            cand[C + 2 * c]     = s_usn[cand[c] * 2 + 0];
            cand[C + 2 * c + 1] = s_usn[cand[c] * 2 + 1];
        }
        int ne = s_ne[nb];
        if (ne > 0) {
            int t = explore_index(i, ne);
            int ex = wtbl[nb * N_UNITS + t];
            cand[T - 1] = ex;
            atomicAdd(&hist[ex * 32 + (nb >> 1)], (nb & 1) ? 0x10000u : 1u);
        } else {
            cand[T - 1] = -1;
        }
        float vc[T], vs[T];
#pragma unroll
        for (int jj = 0; jj < T; ++jj) {
            bool dup = false;
#pragma unroll
            for (int k = 0; k < jj; ++k) dup |= (cand[k] == cand[jj]);
            int v = dup ? -1 : cand[jj];
            vc[jj] = (float)v;
            vs[jj] = (v >= 0) ? s_ll[v] : 0.0f;
        }
        float2* oc2 = (float2*)(out_cand   + (size_t)i * T);
        float2* os2 = (float2*)(out_scores + (size_t)i * T);
#pragma unroll
        for (int jj = 0; jj < T / 2; ++jj) {
            oc2[jj] = make_float2(vc[2 * jj], vc[2 * jj + 1]);
            os2[jj] = make_float2(vs[2 * jj], vs[2 * jj + 1]);
        }
    }
    __syncthreads();
    uint32_t* Pb = PD + (size_t)blockIdx.x * EH;
    for (int k = tid; k < EH; k += BS) Pb[k] = hist[k];
}

__global__ void k_finalE(const uint32_t* __restrict__ PD,
                         float* __restrict__ out_counts) {
    __shared__ uint32_t red[256];
    int tid = threadIdx.x;
    int wl = tid & 63, g = tid >> 6;
    int w = blockIdx.x * 64 + wl;
    uint32_t sum = 0;
#pragma unroll 8
    for (int s = g * (MB / 4); s < (g + 1) * (MB / 4); ++s)
        sum += PD[(size_t)s * EH + w];
    red[tid] = sum;
    __syncthreads();
    if (g == 0) {
        uint32_t tot = red[wl] + red[wl + 64] + red[wl + 128] + red[wl + 192];
        int u = w >> 5, nb2 = (w & 31) * 2;
        float2* p = (float2*)(out_counts + u * N_NEIGHB + nb2);
        float2 v = *p;
        v.x += (float)(tot & 0xFFFFu);
        v.y += (float)(tot >> 16);
        *p = v;
    }
}

extern "C" void kernel_launch(void* const* d_in, const int* in_sizes, int n_in,
                              void* d_out, int out_size, void* d_ws, size_t ws_size,
                              hipStream_t stream) {
    const float* logliks = (const float*)d_in[0];
    const int*   top     = (const int*)d_in[1];
    const int*   usn     = (const int*)d_in[2];
    const int*   nbid    = (const int*)d_in[3];

    int n = in_sizes[3];                                 // N_SPIKES

    float* out        = (float*)d_out;
    float* out_cand   = out;
    float* out_counts = out + (size_t)n * T;
    float* out_scores = out_counts + (size_t)N_UNITS * N_NEIGHB;

    // Scratch in d_ws (~53 MB used of ~320 MB):
    int*      wtbl = (int*)d_ws;                          // [64][400]
    int*      wne  = wtbl + N_NEIGHB * N_UNITS;           // [64]
    uint32_t* PA   = (uint32_t*)(wne + 64);               // GB*HH = 26.2 MB
    uint32_t* PD   = PA + (size_t)GB * HH;                // GB*EH = 26.2 MB
    uint32_t* Hsum = PD + (size_t)GB * EH;                // 25600 words

    int chunkA_f = ((n + SLICE_A - 1) / SLICE_A + 3) & ~3;
    int chunkM_f = (n + GB - 1) / GB;

    void* args[] = { (void*)&logliks, (void*)&top, (void*)&usn, (void*)&nbid,
                     (void*)&wtbl, (void*)&wne, (void*)&PA, (void*)&PD,
                     (void*)&Hsum, (void*)&out_counts, (void*)&out_cand,
                     (void*)&out_scores, (void*)&n, (void*)&chunkA_f,
                     (void*)&chunkM_f };
    hipError_t rc = hipLaunchCooperativeKernel((const void*)k_fused,
                                               dim3(GB), dim3(BS),
                                               args, 0, stream);
    if (rc == hipSuccess) return;
    (void)hipGetLastError();   // clear sticky error, fall back

    // ---- fallback: verified 4-kernel pipeline (round 11) ----
    int chunkA = ((n + NSLICE_A - 1) / NSLICE_A + 3) & ~3;
    int chunkM = (n + MB - 1) / MB;
    k_histA      <<<NSLICE_A * 2, BS, 0, stream>>>(top, nbid, PA, n, chunkA);
    k_tables_base<<<N_NEIGHB, 512, 0, stream>>>(PA, usn, wtbl, wne, out_counts);
    k_main       <<<MB, BS, 0, stream>>>(logliks, top, usn, nbid, wtbl, wne,
                                         PD, out_cand, out_scores, n, chunkM);
    k_finalE     <<<EH / 64, BS, 0, stream>>>(PD, out_counts);
}